// Round 1
// 1067.314 us; speedup vs baseline: 1.0391x; 1.0391x over previous
//
#include <hip/hip_runtime.h>

typedef __bf16 bf16x8 __attribute__((ext_vector_type(8)));
typedef float  f32x4  __attribute__((ext_vector_type(4)));

#define IN_F  4096
#define OUT_F 4096
#define BM 256
#define BN 256
#define BK 32
#define NBUF 4
#define TILE_ELEMS (BM * BK)   // 8192 bf16 = 16 KiB per matrix per buffer

// ---- fp32 -> bf16 (RNE) pack helpers --------------------------------------
__device__ inline unsigned int pk_bf16(float a, float b) {
  unsigned int ua = __float_as_uint(a);
  unsigned int ub = __float_as_uint(b);
  ua = (ua + 0x7FFFu + ((ua >> 16) & 1u)) >> 16;
  ub = (ub + 0x7FFFu + ((ub >> 16) & 1u)) >> 16;
  return ua | (ub << 16);
}
__device__ inline unsigned short bf16_1(float a) {
  unsigned int u = __float_as_uint(a);
  return (unsigned short)((u + 0x7FFFu + ((u >> 16) & 1u)) >> 16);
}

// ---- prep kernels ----------------------------------------------------------
// 8 floats -> 8 bf16 per thread (16B store)
__global__ void cvt_f32_bf16_x8(const float4* __restrict__ src, uint4* __restrict__ dst, int n8) {
  int i = blockIdx.x * 256 + threadIdx.x;
  if (i >= n8) return;
  float4 a = src[2 * i];
  float4 b = src[2 * i + 1];
  uint4 o;
  o.x = pk_bf16(a.x, a.y);
  o.y = pk_bf16(a.z, a.w);
  o.z = pk_bf16(b.x, b.y);
  o.w = pk_bf16(b.z, b.w);
  dst[i] = o;
}

// Sparse fix-up: idx is SORTED. Segment leader sums duplicates in fp32 and
// overwrites the already-converted bf16 weight with bf16(dw + sum).
// Numerically identical to the old fp32-scratch atomic path (fp32 add -> RNE).
__global__ void sparse_fix_k(const float* __restrict__ dw, const int* __restrict__ idx,
                             const float* __restrict__ sv, unsigned short* __restrict__ wb,
                             int nnz) {
  int i = blockIdx.x * 256 + threadIdx.x;
  if (i >= nnz) return;
  int id = idx[i];
  if (i > 0 && idx[i - 1] == id) return;   // not a segment leader
  float s = sv[i];
  int j = i + 1;
  while (j < nnz && idx[j] == id) { s += sv[j]; ++j; }
  wb[id] = bf16_1(dw[id] + s);
}

// ---- bf16 MFMA GEMM, 256x256 tile, counted-vmcnt pipeline ------------------
// 512 threads = 8 waves (2 M x 4 N), each wave owns a 128x64 output sub-tile
// (8x4 grid of 16x16 MFMA fragments). BK=32 (one 16x16x32 k-step per tile).
// LDS: 4 buffers x (A[256][32] + B[256][32]) bf16 = 128 KiB -> 1 block/CU,
// 2 waves/SIMD. Prefetch depth 3: while computing tile t, tile t+3 is staged
// into buf[(t+3)&3] = buf[(t-1)&3] (dead since t-1's last barrier).
// Steady-state wait is s_waitcnt vmcnt(8) (8 newest = tiles t+2,t+3 in
// flight) -> never drains the global_load_lds queue (T3+T4). setprio(1)
// wraps each 16-MFMA cluster (T5). XOR swizzle on the GLOBAL source k-chunk
// (phys = logical ^ ((row>>1)&3)) keeps lane-linear LDS fill and 2-way-max
// (free) ds_read_b128 bank aliasing — same scheme as the verified 128² kernel.
__global__ __launch_bounds__(512, 2) void gemm256(
    const unsigned short* __restrict__ Xb,   // [M][K] bf16
    const unsigned short* __restrict__ Wb,   // [N][K] bf16
    const float* __restrict__ bias,          // [N]
    float* __restrict__ out,                 // [M][N] fp32
    int M, int N, int K)
{
  __shared__ __align__(16) unsigned short lA[NBUF * TILE_ELEMS];  // 64 KiB
  __shared__ __align__(16) unsigned short lB[NBUF * TILE_ELEMS];  // 64 KiB

  const int t    = threadIdx.x;
  const int w    = t >> 6;
  const int lane = t & 63;
  const int quad = lane >> 4;
  const int l16  = lane & 15;
  const int wr   = w >> 2;      // 0..1  (M position of wave)
  const int wc   = w & 3;       // 0..3  (N position of wave)

  // XCD-aware block swizzle (T1). nwg = 1024, divisible by 8 -> bijective.
  const int nwg = gridDim.x;
  const int cpx = nwg >> 3;
  const int sid = (blockIdx.x & 7) * cpx + (blockIdx.x >> 3);
  const int gn  = N / BN;                     // 16
  const int tile_n = (sid % gn) * BN;
  const int tile_m = (sid / gn) * BM;

  // staging decomposition: chunk c = round*512 + t ; row = c>>2 ; k-chunk = c&3
  // source column is XOR-swizzled so LDS stays lane-linear (gload_lds rule).
  const int c0 = t, c1 = 512 + t;
  const int r0 = c0 >> 2, r1 = c1 >> 2;
  const int s0 = ((c0 & 3) ^ ((r0 >> 1) & 3)) * 8;
  const int s1 = ((c1 & 3) ^ ((r1 >> 1) & 3)) * 8;
  const unsigned short* aS0 = Xb + (size_t)(tile_m + r0) * K + s0;
  const unsigned short* aS1 = Xb + (size_t)(tile_m + r1) * K + s1;
  const unsigned short* bS0 = Wb + (size_t)(tile_n + r0) * K + s0;
  const unsigned short* bS1 = Wb + (size_t)(tile_n + r1) * K + s1;

#define GLD(src, dst) __builtin_amdgcn_global_load_lds( \
      (const __attribute__((address_space(1))) unsigned int*)(src), \
      (__attribute__((address_space(3))) unsigned int*)(dst), 16, 0, 0)
#define STAGE_A(tt) do { const int _b = ((tt) & 3) * TILE_ELEMS; const int _kb = (tt) * BK; \
      GLD(aS0 + _kb, lA + _b + c0 * 8); GLD(aS1 + _kb, lA + _b + c1 * 8); } while (0)
#define STAGE_B(tt) do { const int _b = ((tt) & 3) * TILE_ELEMS; const int _kb = (tt) * BK; \
      GLD(bS0 + _kb, lB + _b + c0 * 8); GLD(bS1 + _kb, lB + _b + c1 * 8); } while (0)

  // ds_read fragment offsets (un-swizzle: want logical k-chunk = quad)
  int offA[8], offB[4];
#pragma unroll
  for (int mi = 0; mi < 8; ++mi) {
    const int ra = wr * 128 + mi * 16 + l16;
    offA[mi] = ra * BK + (quad ^ ((ra >> 1) & 3)) * 8;
  }
#pragma unroll
  for (int ni = 0; ni < 4; ++ni) {
    const int rb = wc * 64 + ni * 16 + l16;
    offB[ni] = rb * BK + (quad ^ ((rb >> 1) & 3)) * 8;
  }

  f32x4 acc[8][4] = {};
  const int nt = K / BK;   // 128

  // prologue: stage tiles 0,1,2 (12 loads) and wait for tile 0 (oldest 4)
  STAGE_A(0); STAGE_B(0);
  STAGE_A(1); STAGE_B(1);
  STAGE_A(2); STAGE_B(2);
  asm volatile("s_waitcnt vmcnt(8)" ::: "memory");
  __builtin_amdgcn_s_barrier();

  for (int tt = 0; tt < nt; ++tt) {
    const unsigned short* bufA = lA + (tt & 3) * TILE_ELEMS;
    const unsigned short* bufB = lB + (tt & 3) * TILE_ELEMS;

    // ---- phase alpha: mi 0..3 x ni 0..3 (16 MFMA) ----
    bf16x8 af0[4], bfr[4];
#pragma unroll
    for (int mi = 0; mi < 4; ++mi) af0[mi] = *(const bf16x8*)&bufA[offA[mi]];
#pragma unroll
    for (int ni = 0; ni < 4; ++ni) bfr[ni] = *(const bf16x8*)&bufB[offB[ni]];
    if (tt + 3 < nt) STAGE_A(tt + 3);
    __builtin_amdgcn_s_barrier();
    __builtin_amdgcn_s_setprio(1);
#pragma unroll
    for (int mi = 0; mi < 4; ++mi)
#pragma unroll
      for (int ni = 0; ni < 4; ++ni)
        acc[mi][ni] = __builtin_amdgcn_mfma_f32_16x16x32_bf16(af0[mi], bfr[ni], acc[mi][ni], 0, 0, 0);
    __builtin_amdgcn_s_setprio(0);
    __builtin_amdgcn_s_barrier();

    // ---- phase beta: mi 4..7 x ni 0..3 (16 MFMA, B frags reused in regs) ----
    bf16x8 af1[4];
#pragma unroll
    for (int mi = 0; mi < 4; ++mi) af1[mi] = *(const bf16x8*)&bufA[offA[4 + mi]];
    if (tt + 3 < nt) STAGE_B(tt + 3);
    // counted vmcnt: 8 newest outstanding = tiles tt+2, tt+3 -> tile tt+1 landed
    if (tt < nt - 3)       asm volatile("s_waitcnt vmcnt(8)" ::: "memory");
    else if (tt == nt - 3) asm volatile("s_waitcnt vmcnt(4)" ::: "memory");
    else if (tt == nt - 2) asm volatile("s_waitcnt vmcnt(0)" ::: "memory");
    __builtin_amdgcn_s_barrier();
    __builtin_amdgcn_s_setprio(1);
#pragma unroll
    for (int mi = 0; mi < 4; ++mi)
#pragma unroll
      for (int ni = 0; ni < 4; ++ni)
        acc[4 + mi][ni] = __builtin_amdgcn_mfma_f32_16x16x32_bf16(af1[mi], bfr[ni], acc[4 + mi][ni], 0, 0, 0);
    __builtin_amdgcn_s_setprio(0);
    __builtin_amdgcn_s_barrier();
  }

  // epilogue: D lane mapping col = lane&15, row = quad*4 + reg (m89/m91-verified)
#pragma unroll
  for (int ni = 0; ni < 4; ++ni) {
    const int n = tile_n + wc * 64 + ni * 16 + l16;
    const float bv = bias[n];
#pragma unroll
    for (int mi = 0; mi < 8; ++mi) {
      const int m0 = tile_m + wr * 128 + mi * 16 + quad * 4;
#pragma unroll
      for (int r = 0; r < 4; ++r)
        out[(size_t)(m0 + r) * N + n] = acc[mi][ni][r] + bv;
    }
  }
#undef GLD
#undef STAGE_A
#undef STAGE_B
}

// ---- launch ----------------------------------------------------------------
extern "C" void kernel_launch(void* const* d_in, const int* in_sizes, int n_in,
                              void* d_out, int out_size, void* d_ws, size_t ws_size,
                              hipStream_t stream) {
  const float* x    = (const float*)d_in[0];  // [8,2048,4096]
  const float* dw   = (const float*)d_in[1];  // [4096,4096]
  const float* bias = (const float*)d_in[2];  // [4096]
  const float* sv   = (const float*)d_in[3];  // [NNZ]
  const int*   idx  = (const int*)d_in[4];    // [NNZ] sorted flat indices
  float* out = (float*)d_out;

  const int K = IN_F, N = OUT_F;
  const int M   = in_sizes[0] / K;   // 16384 tokens
  const int nnz = in_sizes[3];
  const int WN  = N * K;             // 16,777,216

  // workspace: [X bf16 128MB][W bf16 32MB] = 160 MB
  unsigned short* ws_xb = (unsigned short*)d_ws;
  unsigned short* ws_wb = (unsigned short*)((char*)d_ws + (size_t)in_sizes[0] * 2);

  // 1) dense W fp32 -> bf16 (direct from input; no fp32 scratch copy)
  cvt_f32_bf16_x8<<<WN / 8 / 256, 256, 0, stream>>>((const float4*)dw, (uint4*)ws_wb, WN / 8);
  // 2) sparse fix-up (sorted idx, segment-leader handles duplicates; no atomics)
  sparse_fix_k<<<(nnz + 255) / 256, 256, 0, stream>>>(dw, idx, sv, ws_wb, nnz);
  // 3) X fp32 -> bf16
  const int xn = in_sizes[0];
  cvt_f32_bf16_x8<<<xn / 8 / 256, 256, 0, stream>>>((const float4*)x, (uint4*)ws_xb, xn / 8);
  // 4) 256x256 counted-vmcnt bf16 MFMA GEMM + bias
  const int nblocks = (M / BM) * (N / BN);   // 64*16 = 1024
  gemm256<<<nblocks, 512, 0, stream>>>(ws_xb, ws_wb, bias, out, M, N, K);
}

// Round 2
// 1059.101 us; speedup vs baseline: 1.0472x; 1.0078x over previous
//
#include <hip/hip_runtime.h>

typedef __bf16 bf16x8 __attribute__((ext_vector_type(8)));
typedef float  f32x4  __attribute__((ext_vector_type(4)));

#define IN_F  4096
#define OUT_F 4096
#define BM 256
#define BN 256
#define BK 64                       // K-tile; staged as two k-halves of 32
#define HALF_ELEMS (BM * 32)        // 8192 bf16 = 16 KiB per half-tile
#define TILE_ELEMS (BM * BK)        // 16384 bf16 = 32 KiB per tile per matrix

// ---- fp32 -> bf16 (RNE) pack helpers --------------------------------------
__device__ inline unsigned int pk_bf16(float a, float b) {
  unsigned int ua = __float_as_uint(a);
  unsigned int ub = __float_as_uint(b);
  ua = (ua + 0x7FFFu + ((ua >> 16) & 1u)) >> 16;
  ub = (ub + 0x7FFFu + ((ub >> 16) & 1u)) >> 16;
  return ua | (ub << 16);
}
__device__ inline unsigned short bf16_1(float a) {
  unsigned int u = __float_as_uint(a);
  return (unsigned short)((u + 0x7FFFu + ((u >> 16) & 1u)) >> 16);
}

// ---- prep kernels ----------------------------------------------------------
__global__ void cvt_f32_bf16_x8(const float4* __restrict__ src, uint4* __restrict__ dst, int n8) {
  int i = blockIdx.x * 256 + threadIdx.x;
  if (i >= n8) return;
  float4 a = src[2 * i];
  float4 b = src[2 * i + 1];
  uint4 o;
  o.x = pk_bf16(a.x, a.y);
  o.y = pk_bf16(a.z, a.w);
  o.z = pk_bf16(b.x, b.y);
  o.w = pk_bf16(b.z, b.w);
  dst[i] = o;
}

// Sparse fix-up: idx SORTED; segment leader sums duplicates in fp32 and
// overwrites the converted bf16 weight with bf16(dw + sum).
__global__ void sparse_fix_k(const float* __restrict__ dw, const int* __restrict__ idx,
                             const float* __restrict__ sv, unsigned short* __restrict__ wb,
                             int nnz) {
  int i = blockIdx.x * 256 + threadIdx.x;
  if (i >= nnz) return;
  int id = idx[i];
  if (i > 0 && idx[i - 1] == id) return;
  float s = sv[i];
  int j = i + 1;
  while (j < nnz && idx[j] == id) { s += sv[j]; ++j; }
  wb[id] = bf16_1(dw[id] + s);
}

// ---- bf16 MFMA GEMM, 256x256 tile, m201-style 4-phase/K-tile pipeline ------
// 512 thr = 8 waves (2M x 4N), wave owns 128x64 out (8x4 frags). BK=64 ->
// 64 MFMA / K-tile / wave, split into 4 phases x 16 MFMA:
//   p0: reads A[0..3]ks0 + B[0..3]ks0 (8 ds_read) ; MFMA mi0-3 x ni0-3, ks0
//   p1: reads A[4..7]ks0 (4)                      ; MFMA mi4-7, ks0
//   p2: reads A[0..3]ks1 + B[0..3]ks1 (8)         ; MFMA mi0-3, ks1
//   p3: reads A[4..7]ks1 (4)                      ; MFMA mi4-7, ks1
// Staging granularity = k-half-tile (256x32 bf16 = 16 KiB = 2 gload_lds/thr),
// ONE half-tile per phase, stream Δ=6 phases ahead of first use:
//   p0 stages (T+1,A,h1); p1 (T+1,B,h1); p2 (T+2,A,h0); p3 (T+2,B,h0)
// Half-recycling makes 2 buffers sustain the 1.5-tile prefetch: (T+2,*,h0)
// overwrites tile T's own h0, dead after p1's end barrier (its last reader).
// vmcnt(8) per phase is exactly tight: 8 newest loads = 4 newest half-tiles
// = items I_{phi+3}..I_{phi+6}; next phase reads only items <= I_{phi+2}.
// Tail: one vmcnt(0) drain, then the last K-tile runs barrier-free.
// Source-side XOR swizzle (phys k-chunk = logical ^ ((row>>1)&3)) keeps the
// gload_lds dest lane-linear and ds_read_b128 conflict-free (0 measured).
__global__ __launch_bounds__(512, 2) void gemm256(
    const unsigned short* __restrict__ Xb,   // [M][K] bf16
    const unsigned short* __restrict__ Wb,   // [N][K] bf16
    const float* __restrict__ bias,          // [N]
    float* __restrict__ out,                 // [M][N] fp32
    int M, int N, int K)
{
  __shared__ __align__(16) unsigned short lA[2 * TILE_ELEMS];  // 64 KiB
  __shared__ __align__(16) unsigned short lB[2 * TILE_ELEMS];  // 64 KiB

  const int t    = threadIdx.x;
  const int w    = t >> 6;
  const int lane = t & 63;
  const int quad = lane >> 4;
  const int l16  = lane & 15;
  const int wr   = w >> 2;      // 0..1
  const int wc   = w & 3;       // 0..3

  // XCD-aware bijective block swizzle (nwg = 1024, %8 == 0)
  const int nwg = gridDim.x;
  const int cpx = nwg >> 3;
  const int sid = (blockIdx.x & 7) * cpx + (blockIdx.x >> 3);
  const int gn  = N / BN;
  const int tile_n = (sid % gn) * BN;
  const int tile_m = (sid / gn) * BM;

  // staging: chunk c = round*512 + t ; row = c>>2 ; k-chunk = c&3 (8 elems)
  const int c0 = t, c1 = 512 + t;
  const int r0 = c0 >> 2, r1 = c1 >> 2;
  const int s0 = ((c0 & 3) ^ ((r0 >> 1) & 3)) * 8;   // swizzled source col
  const int s1 = ((c1 & 3) ^ ((r1 >> 1) & 3)) * 8;
  const unsigned short* AS0 = Xb + (size_t)(tile_m + r0) * K + s0;
  const unsigned short* AS1 = Xb + (size_t)(tile_m + r1) * K + s1;
  const unsigned short* BS0 = Wb + (size_t)(tile_n + r0) * K + s0;
  const unsigned short* BS1 = Wb + (size_t)(tile_n + r1) * K + s1;

#define GLD(src, dst) __builtin_amdgcn_global_load_lds( \
      (const __attribute__((address_space(1))) unsigned int*)(src), \
      (__attribute__((address_space(3))) unsigned int*)(dst), 16, 0, 0)
  // stage half-tile (MAT, tile TT, k-half H) : dest lane-linear, 2 loads/thr
#define STAGE(MAT, TT, H) do { \
      const int _b = (((TT) & 1) << 14) + ((H) << 13); \
      const int _k = ((TT) << 6) + ((H) << 5); \
      GLD(MAT##S0 + _k, l##MAT + _b + c0 * 8); \
      GLD(MAT##S1 + _k, l##MAT + _b + c1 * 8); } while (0)
#define WAITV(n) asm volatile("s_waitcnt vmcnt(" #n ")" ::: "memory")
#define BAR() __builtin_amdgcn_s_barrier()

  // ds_read fragment element offsets within a k-half [256][32]
  int offA[8], offB[4];
#pragma unroll
  for (int mi = 0; mi < 8; ++mi) {
    const int ra = wr * 128 + mi * 16 + l16;
    offA[mi] = ra * 32 + (quad ^ ((ra >> 1) & 3)) * 8;
  }
#pragma unroll
  for (int ni = 0; ni < 4; ++ni) {
    const int rb = wc * 64 + ni * 16 + l16;
    offB[ni] = rb * 32 + (quad ^ ((rb >> 1) & 3)) * 8;
  }

  f32x4 acc[8][4] = {};
  bf16x8 a0[4], a1[4], b0[4], b1[4];
  const int NT = K / BK;   // 64

  // prologue: items I0..I5 = (0,A,h0),(0,B,h0),(0,A,h1),(0,B,h1),(1,A,h0),(1,B,h0)
  STAGE(A, 0, 0); STAGE(B, 0, 0);
  STAGE(A, 0, 1); STAGE(B, 0, 1);
  STAGE(A, 1, 0); STAGE(B, 1, 0);
  WAITV(8);   // I0,I1 landed (newest 8 loads = I2..I5)
  BAR();

  for (int T = 0; T < NT - 1; ++T) {
    const unsigned short* bufA = lA + ((T & 1) << 14);
    const unsigned short* bufB = lB + ((T & 1) << 14);
    const bool st2 = (T + 2 < NT);

    // ---- p0 ----
#pragma unroll
    for (int i = 0; i < 4; ++i) a0[i] = *(const bf16x8*)&bufA[offA[i]];
#pragma unroll
    for (int j = 0; j < 4; ++j) b0[j] = *(const bf16x8*)&bufB[offB[j]];
    STAGE(A, T + 1, 1);
    WAITV(8); BAR();
    __builtin_amdgcn_s_setprio(1);
#pragma unroll
    for (int i = 0; i < 4; ++i)
#pragma unroll
      for (int j = 0; j < 4; ++j)
        acc[i][j] = __builtin_amdgcn_mfma_f32_16x16x32_bf16(a0[i], b0[j], acc[i][j], 0, 0, 0);
    __builtin_amdgcn_s_setprio(0);
    BAR();

    // ---- p1 ----
#pragma unroll
    for (int i = 0; i < 4; ++i) a1[i] = *(const bf16x8*)&bufA[offA[4 + i]];
    STAGE(B, T + 1, 1);
    WAITV(8); BAR();
    __builtin_amdgcn_s_setprio(1);
#pragma unroll
    for (int i = 0; i < 4; ++i)
#pragma unroll
      for (int j = 0; j < 4; ++j)
        acc[4 + i][j] = __builtin_amdgcn_mfma_f32_16x16x32_bf16(a1[i], b0[j], acc[4 + i][j], 0, 0, 0);
    __builtin_amdgcn_s_setprio(0);
    BAR();

    // ---- p2 ----
#pragma unroll
    for (int i = 0; i < 4; ++i) a0[i] = *(const bf16x8*)&bufA[HALF_ELEMS + offA[i]];
#pragma unroll
    for (int j = 0; j < 4; ++j) b1[j] = *(const bf16x8*)&bufB[HALF_ELEMS + offB[j]];
    if (st2) STAGE(A, T + 2, 0);   // overwrites tile T's own h0 (dead after p1)
    WAITV(8); BAR();
    __builtin_amdgcn_s_setprio(1);
#pragma unroll
    for (int i = 0; i < 4; ++i)
#pragma unroll
      for (int j = 0; j < 4; ++j)
        acc[i][j] = __builtin_amdgcn_mfma_f32_16x16x32_bf16(a0[i], b1[j], acc[i][j], 0, 0, 0);
    __builtin_amdgcn_s_setprio(0);
    BAR();

    // ---- p3 ----
#pragma unroll
    for (int i = 0; i < 4; ++i) a1[i] = *(const bf16x8*)&bufA[HALF_ELEMS + offA[4 + i]];
    if (st2) STAGE(B, T + 2, 0);
    WAITV(8); BAR();
    __builtin_amdgcn_s_setprio(1);
#pragma unroll
    for (int i = 0; i < 4; ++i)
#pragma unroll
      for (int j = 0; j < 4; ++j)
        acc[4 + i][j] = __builtin_amdgcn_mfma_f32_16x16x32_bf16(a1[i], b1[j], acc[4 + i][j], 0, 0, 0);
    __builtin_amdgcn_s_setprio(0);
    BAR();
  }

  // ---- last K-tile: everything staged; drain once, then barrier-free ----
  {
    const int T = NT - 1;
    WAITV(0); BAR();
    const unsigned short* bufA = lA + ((T & 1) << 14);
    const unsigned short* bufB = lB + ((T & 1) << 14);
#pragma unroll
    for (int i = 0; i < 4; ++i) a0[i] = *(const bf16x8*)&bufA[offA[i]];
#pragma unroll
    for (int j = 0; j < 4; ++j) b0[j] = *(const bf16x8*)&bufB[offB[j]];
#pragma unroll
    for (int i = 0; i < 4; ++i)
#pragma unroll
      for (int j = 0; j < 4; ++j)
        acc[i][j] = __builtin_amdgcn_mfma_f32_16x16x32_bf16(a0[i], b0[j], acc[i][j], 0, 0, 0);
#pragma unroll
    for (int i = 0; i < 4; ++i) a1[i] = *(const bf16x8*)&bufA[offA[4 + i]];
#pragma unroll
    for (int i = 0; i < 4; ++i)
#pragma unroll
      for (int j = 0; j < 4; ++j)
        acc[4 + i][j] = __builtin_amdgcn_mfma_f32_16x16x32_bf16(a1[i], b0[j], acc[4 + i][j], 0, 0, 0);
#pragma unroll
    for (int i = 0; i < 4; ++i) a0[i] = *(const bf16x8*)&bufA[HALF_ELEMS + offA[i]];
#pragma unroll
    for (int j = 0; j < 4; ++j) b1[j] = *(const bf16x8*)&bufB[HALF_ELEMS + offB[j]];
#pragma unroll
    for (int i = 0; i < 4; ++i)
#pragma unroll
      for (int j = 0; j < 4; ++j)
        acc[i][j] = __builtin_amdgcn_mfma_f32_16x16x32_bf16(a0[i], b1[j], acc[i][j], 0, 0, 0);
#pragma unroll
    for (int i = 0; i < 4; ++i) a1[i] = *(const bf16x8*)&bufA[HALF_ELEMS + offA[4 + i]];
#pragma unroll
    for (int i = 0; i < 4; ++i)
#pragma unroll
      for (int j = 0; j < 4; ++j)
        acc[4 + i][j] = __builtin_amdgcn_mfma_f32_16x16x32_bf16(a1[i], b1[j], acc[4 + i][j], 0, 0, 0);
  }

  // epilogue: D lane mapping col = lane&15, row = quad*4 + reg (m89/m91)
#pragma unroll
  for (int ni = 0; ni < 4; ++ni) {
    const int n = tile_n + wc * 64 + ni * 16 + l16;
    const float bv = bias[n];
#pragma unroll
    for (int mi = 0; mi < 8; ++mi) {
      const int m0 = tile_m + wr * 128 + mi * 16 + quad * 4;
#pragma unroll
      for (int r = 0; r < 4; ++r)
        out[(size_t)(m0 + r) * N + n] = acc[mi][ni][r] + bv;
    }
  }
#undef GLD
#undef STAGE
#undef WAITV
#undef BAR
}

// ---- launch ----------------------------------------------------------------
extern "C" void kernel_launch(void* const* d_in, const int* in_sizes, int n_in,
                              void* d_out, int out_size, void* d_ws, size_t ws_size,
                              hipStream_t stream) {
  const float* x    = (const float*)d_in[0];  // [8,2048,4096]
  const float* dw   = (const float*)d_in[1];  // [4096,4096]
  const float* bias = (const float*)d_in[2];  // [4096]
  const float* sv   = (const float*)d_in[3];  // [NNZ]
  const int*   idx  = (const int*)d_in[4];    // [NNZ] sorted flat indices
  float* out = (float*)d_out;

  const int K = IN_F, N = OUT_F;
  const int M   = in_sizes[0] / K;   // 16384 tokens
  const int nnz = in_sizes[3];
  const int WN  = N * K;             // 16,777,216

  // workspace: [X bf16 128MB][W bf16 32MB]
  unsigned short* ws_xb = (unsigned short*)d_ws;
  unsigned short* ws_wb = (unsigned short*)((char*)d_ws + (size_t)in_sizes[0] * 2);

  // 1) dense W fp32 -> bf16
  cvt_f32_bf16_x8<<<WN / 8 / 256, 256, 0, stream>>>((const float4*)dw, (uint4*)ws_wb, WN / 8);
  // 2) sparse fix-up (sorted idx, segment leaders; no atomics)
  sparse_fix_k<<<(nnz + 255) / 256, 256, 0, stream>>>(dw, idx, sv, ws_wb, nnz);
  // 3) X fp32 -> bf16
  const int xn = in_sizes[0];
  cvt_f32_bf16_x8<<<xn / 8 / 256, 256, 0, stream>>>((const float4*)x, (uint4*)ws_xb, xn / 8);
  // 4) 256x256 4-phase counted-vmcnt bf16 MFMA GEMM + bias
  const int nblocks = (M / BM) * (N / BN);   // 1024
  gemm256<<<nblocks, 512, 0, stream>>>(ws_xb, ws_wb, bias, out, M, N, K);
}

// Round 3
// 1000.270 us; speedup vs baseline: 1.1088x; 1.0588x over previous
//
#include <hip/hip_runtime.h>

typedef __bf16 bf16x8 __attribute__((ext_vector_type(8)));
typedef float  f32x4  __attribute__((ext_vector_type(4)));

#define IN_F  4096
#define OUT_F 4096
#define BM 256
#define BN 256
#define BK 64                       // K-tile; staged as two k-halves of 32
#define HALF_ELEMS (BM * 32)        // 8192 bf16 = 16 KiB per half-tile
#define TILE_ELEMS (BM * BK)        // 16384 bf16 = 32 KiB per tile per matrix

// ---- fp32 -> bf16 (RNE) pack helpers --------------------------------------
__device__ inline unsigned int pk_bf16(float a, float b) {
  unsigned int ua = __float_as_uint(a);
  unsigned int ub = __float_as_uint(b);
  ua = (ua + 0x7FFFu + ((ua >> 16) & 1u)) >> 16;
  ub = (ub + 0x7FFFu + ((ub >> 16) & 1u)) >> 16;
  return ua | (ub << 16);
}
__device__ inline unsigned short bf16_1(float a) {
  unsigned int u = __float_as_uint(a);
  return (unsigned short)((u + 0x7FFFu + ((u >> 16) & 1u)) >> 16);
}

// ---- prep kernels ----------------------------------------------------------
__global__ void cvt_f32_bf16_x8(const float4* __restrict__ src, uint4* __restrict__ dst, int n8) {
  int i = blockIdx.x * 256 + threadIdx.x;
  if (i >= n8) return;
  float4 a = src[2 * i];
  float4 b = src[2 * i + 1];
  uint4 o;
  o.x = pk_bf16(a.x, a.y);
  o.y = pk_bf16(a.z, a.w);
  o.z = pk_bf16(b.x, b.y);
  o.w = pk_bf16(b.z, b.w);
  dst[i] = o;
}

// Sparse fix-up: idx SORTED; segment leader sums duplicates in fp32 and
// overwrites the converted bf16 weight with bf16(dw + sum).
__global__ void sparse_fix_k(const float* __restrict__ dw, const int* __restrict__ idx,
                             const float* __restrict__ sv, unsigned short* __restrict__ wb,
                             int nnz) {
  int i = blockIdx.x * 256 + threadIdx.x;
  if (i >= nnz) return;
  int id = idx[i];
  if (i > 0 && idx[i - 1] == id) return;
  float s = sv[i];
  int j = i + 1;
  while (j < nnz && idx[j] == id) { s += sv[j]; ++j; }
  wb[id] = bf16_1(dw[id] + s);
}

// ---- bf16 MFMA GEMM, 256x256 tile, m201-faithful 4-phase/K-tile pipeline ---
// 512 thr = 8 waves (2M x 4N), wave owns 128x64 out (8x4 frags). BK=64 ->
// 64 MFMA / K-tile / wave, 4 phases x 16 MFMA:
//   p0: rd A[0..3]h0 + B[0..3]h0 (8 ds_read); stage (T+1,A,h1);        BAR MFMA BAR
//   p1: rd A[4..7]h0 (4);                     stage (T+1,B,h1); vmcnt8 BAR MFMA BAR
//   p2: rd A[0..3]h1 + B[0..3]h1 (8);         stage (T+2,A,h0);        BAR MFMA BAR
//   p3: rd A[4..7]h1 (4);                     stage (T+2,B,h0); vmcnt8 BAR MFMA BAR
// vmcnt ONLY twice per K-tile (template: "phases 4 and 8, never 0"):
//   p1's vmcnt(8) lands items through (T,B,h1)  -> exactly what p2/p3 read.
//   p3's vmcnt(8) lands items through (T+1,B,h0) -> exactly what T+1 p0/p1 read.
// Main loop = 2 K-tiles/iter so every LDS base is a compile-time constant.
// Half-recycling: (T+2,*,h0) overwrites tile T's own h0, dead after p1's end
// barrier (last reader's lgkm-wait precedes its MFMA precedes that barrier).
// Tail: stage (63,*,h1), one vmcnt(0) drain, two barrier-free tiles.
// Source-side XOR swizzle (phys k-chunk = logical ^ ((row>>1)&3)) keeps the
// gload_lds dest lane-linear and ds_read_b128 conflict-free (0 measured).
__global__ __launch_bounds__(512, 2) void gemm256(
    const unsigned short* __restrict__ Xb,   // [M][K] bf16
    const unsigned short* __restrict__ Wb,   // [N][K] bf16
    const float* __restrict__ bias,          // [N]
    float* __restrict__ out,                 // [M][N] fp32
    int M, int N, int K)
{
  __shared__ __align__(16) unsigned short lA[2 * TILE_ELEMS];  // 64 KiB
  __shared__ __align__(16) unsigned short lB[2 * TILE_ELEMS];  // 64 KiB

  const int t    = threadIdx.x;
  const int w    = t >> 6;
  const int lane = t & 63;
  const int quad = lane >> 4;
  const int l16  = lane & 15;
  const int wr   = w >> 2;      // 0..1
  const int wc   = w & 3;       // 0..3

  // XCD-aware bijective block swizzle (nwg = 1024, %8 == 0)
  const int nwg = gridDim.x;
  const int cpx = nwg >> 3;
  const int sid = (blockIdx.x & 7) * cpx + (blockIdx.x >> 3);
  const int gn  = N / BN;
  const int tile_n = (sid % gn) * BN;
  const int tile_m = (sid / gn) * BM;

  // staging: chunk c = round*512 + t ; row = c>>2 ; k-chunk = c&3 (8 elems)
  const int c0 = t, c1 = 512 + t;
  const int r0 = c0 >> 2, r1 = c1 >> 2;
  const int s0 = ((c0 & 3) ^ ((r0 >> 1) & 3)) * 8;   // swizzled source col
  const int s1 = ((c1 & 3) ^ ((r1 >> 1) & 3)) * 8;
  const unsigned short* AS0 = Xb + (size_t)(tile_m + r0) * K + s0;
  const unsigned short* AS1 = Xb + (size_t)(tile_m + r1) * K + s1;
  const unsigned short* BS0 = Wb + (size_t)(tile_n + r0) * K + s0;
  const unsigned short* BS1 = Wb + (size_t)(tile_n + r1) * K + s1;

#define GLD(src, dst) __builtin_amdgcn_global_load_lds( \
      (const __attribute__((address_space(1))) unsigned int*)(src), \
      (__attribute__((address_space(3))) unsigned int*)(dst), 16, 0, 0)
  // stage half-tile (MAT, tile TT, k-half H) : dest lane-linear, 2 loads/thr
#define STAGE(MAT, TT, H) do { \
      const int _b = (((TT) & 1) << 14) + ((H) << 13); \
      const int _k = ((TT) << 6) + ((H) << 5); \
      GLD(MAT##S0 + _k, l##MAT + _b + c0 * 8); \
      GLD(MAT##S1 + _k, l##MAT + _b + c1 * 8); } while (0)
#define WAITV(n) asm volatile("s_waitcnt vmcnt(" #n ")" ::: "memory")
#define BAR() __builtin_amdgcn_s_barrier()

  // ds_read fragment element offsets within a k-half [256][32]
  int offA[8], offB[4];
#pragma unroll
  for (int mi = 0; mi < 8; ++mi) {
    const int ra = wr * 128 + mi * 16 + l16;
    offA[mi] = ra * 32 + (quad ^ ((ra >> 1) & 3)) * 8;
  }
#pragma unroll
  for (int ni = 0; ni < 4; ++ni) {
    const int rb = wc * 64 + ni * 16 + l16;
    offB[ni] = rb * 32 + (quad ^ ((rb >> 1) & 3)) * 8;
  }

  f32x4 acc[8][4] = {};
  bf16x8 a0[4], a1[4], b0[4], b1[4];
  const int NT = K / BK;   // 64

  // 4 ds_read_b128 cluster (off = offA / offA+4 / offB; constant idx after inline)
  auto rd4 = [&](bf16x8* d, const unsigned short* base, const int* off) {
#pragma unroll
    for (int i = 0; i < 4; ++i) d[i] = *(const bf16x8*)&base[off[i]];
  };
  // 16-MFMA cluster into acc rows R..R+3 (R literal at call site -> static idx)
  auto mf = [&](const int R, const bf16x8* at, const bf16x8* bt) {
    __builtin_amdgcn_s_setprio(1);
#pragma unroll
    for (int i = 0; i < 4; ++i)
#pragma unroll
      for (int j = 0; j < 4; ++j)
        acc[R + i][j] = __builtin_amdgcn_mfma_f32_16x16x32_bf16(at[i], bt[j], acc[R + i][j], 0, 0, 0);
    __builtin_amdgcn_s_setprio(0);
  };

  // one K-tile, 4 phases; BB is a literal (0 or TILE_ELEMS)
#define TILE_PHASES(BB, TT)                                                   \
    rd4(a0, lA + (BB), offA); rd4(b0, lB + (BB), offB);                       \
    STAGE(A, (TT) + 1, 1);                                                    \
    BAR(); mf(0, a0, b0); BAR();                                              \
    rd4(a1, lA + (BB), offA + 4);                                             \
    STAGE(B, (TT) + 1, 1);                                                    \
    WAITV(8); BAR(); mf(4, a1, b0); BAR();                                    \
    rd4(a0, lA + (BB) + HALF_ELEMS, offA); rd4(b1, lB + (BB) + HALF_ELEMS, offB); \
    STAGE(A, (TT) + 2, 0);                                                    \
    BAR(); mf(0, a0, b1); BAR();                                              \
    rd4(a1, lA + (BB) + HALF_ELEMS, offA + 4);                                \
    STAGE(B, (TT) + 2, 0);                                                    \
    WAITV(8); BAR(); mf(4, a1, b1); BAR();

  // fully-staged K-tile (after vmcnt(0) drain): no barriers/waits needed
#define TILE_DRAINED(BB)                                                      \
    rd4(a0, lA + (BB), offA); rd4(b0, lB + (BB), offB);                       \
    mf(0, a0, b0);                                                            \
    rd4(a1, lA + (BB), offA + 4); mf(4, a1, b0);                              \
    rd4(a0, lA + (BB) + HALF_ELEMS, offA); rd4(b1, lB + (BB) + HALF_ELEMS, offB); \
    mf(0, a0, b1);                                                            \
    rd4(a1, lA + (BB) + HALF_ELEMS, offA + 4); mf(4, a1, b1);

  // prologue: items (0,A,h0),(0,B,h0),(0,A,h1),(0,B,h1),(1,A,h0),(1,B,h0)
  STAGE(A, 0, 0); STAGE(B, 0, 0);
  STAGE(A, 0, 1); STAGE(B, 0, 1);
  STAGE(A, 1, 0); STAGE(B, 1, 0);
  WAITV(8);   // (0,h0) pair landed
  BAR();

  // main loop: 2 K-tiles per iteration, compile-time LDS bases
  for (int T = 0; T < NT - 2; T += 2) {
    TILE_PHASES(0, T)
    TILE_PHASES(TILE_ELEMS, T + 1)
  }

  // tail: tiles NT-2 (base 0) and NT-1 (base TILE_ELEMS)
  STAGE(A, NT - 1, 1); STAGE(B, NT - 1, 1);
  WAITV(0); BAR();
  TILE_DRAINED(0)
  TILE_DRAINED(TILE_ELEMS)

  // epilogue: D lane mapping col = lane&15, row = quad*4 + reg (m89/m91)
#pragma unroll
  for (int ni = 0; ni < 4; ++ni) {
    const int n = tile_n + wc * 64 + ni * 16 + l16;
    const float bv = bias[n];
#pragma unroll
    for (int mi = 0; mi < 8; ++mi) {
      const int m0 = tile_m + wr * 128 + mi * 16 + quad * 4;
#pragma unroll
      for (int r = 0; r < 4; ++r)
        out[(size_t)(m0 + r) * N + n] = acc[mi][ni][r] + bv;
    }
  }
#undef GLD
#undef STAGE
#undef WAITV
#undef BAR
#undef TILE_PHASES
#undef TILE_DRAINED
}

// ---- launch ----------------------------------------------------------------
extern "C" void kernel_launch(void* const* d_in, const int* in_sizes, int n_in,
                              void* d_out, int out_size, void* d_ws, size_t ws_size,
                              hipStream_t stream) {
  const float* x    = (const float*)d_in[0];  // [8,2048,4096]
  const float* dw   = (const float*)d_in[1];  // [4096,4096]
  const float* bias = (const float*)d_in[2];  // [4096]
  const float* sv   = (const float*)d_in[3];  // [NNZ]
  const int*   idx  = (const int*)d_in[4];    // [NNZ] sorted flat indices
  float* out = (float*)d_out;

  const int K = IN_F, N = OUT_F;
  const int M   = in_sizes[0] / K;   // 16384 tokens
  const int nnz = in_sizes[3];
  const int WN  = N * K;             // 16,777,216

  // workspace: [X bf16 128MB][W bf16 32MB]
  unsigned short* ws_xb = (unsigned short*)d_ws;
  unsigned short* ws_wb = (unsigned short*)((char*)d_ws + (size_t)in_sizes[0] * 2);

  // 1) dense W fp32 -> bf16
  cvt_f32_bf16_x8<<<WN / 8 / 256, 256, 0, stream>>>((const float4*)dw, (uint4*)ws_wb, WN / 8);
  // 2) sparse fix-up (sorted idx, segment leaders; no atomics)
  sparse_fix_k<<<(nnz + 255) / 256, 256, 0, stream>>>(dw, idx, sv, ws_wb, nnz);
  // 3) X fp32 -> bf16
  const int xn = in_sizes[0];
  cvt_f32_bf16_x8<<<xn / 8 / 256, 256, 0, stream>>>((const float4*)x, (uint4*)ws_xb, xn / 8);
  // 4) 256x256 4-phase counted-vmcnt bf16 MFMA GEMM + bias
  const int nblocks = (M / BM) * (N / BN);   // 1024
  gemm256<<<nblocks, 512, 0, stream>>>(ws_xb, ws_wb, bias, out, M, N, K);
}